// Round 1
// baseline (10177.942 us; speedup 1.0000x reference)
//
#include <hip/hip_runtime.h>

typedef _Float16 f16;
typedef f16   f16x8 __attribute__((ext_vector_type(8)));
typedef float f32x4 __attribute__((ext_vector_type(4)));

#define T_LEN 512
#define BATCH 64
#define HID   512

// ---------- helpers ----------
__device__ __forceinline__ float sigm(float x) { return 1.0f / (1.0f + __expf(-x)); }
__device__ __forceinline__ float tanh_f(float x) {
  x = fminf(fmaxf(x, -15.0f), 15.0f);
  float e = __expf(2.0f * x);
  return (e - 1.0f) / (e + 1.0f);
}

// Cross-WG barrier: per-step counter, agent-scope release/acquire for
// cross-XCD visibility of the plain h/c stores (per-XCD L2s not coherent).
__device__ __forceinline__ void wg_barrier(unsigned* ctr, unsigned target) {
  __syncthreads();                       // all stores of this WG issued (vmcnt drained)
  if (threadIdx.x == 0) {
    __builtin_amdgcn_fence(__ATOMIC_RELEASE, "agent");   // wbL2: push our XCD's dirty lines
    __hip_atomic_fetch_add(ctr, 1u, __ATOMIC_RELAXED, __HIP_MEMORY_SCOPE_AGENT);
    while (__hip_atomic_load(ctr, __ATOMIC_RELAXED, __HIP_MEMORY_SCOPE_AGENT) < target) {}
    __builtin_amdgcn_fence(__ATOMIC_ACQUIRE, "agent");   // inv L1/L2 before re-reading h
  }
  __syncthreads();
}

// ---------- x transpose: xT[t][b] = x[b][t] ----------
__global__ void xpose(const float* __restrict__ x, float* __restrict__ xT) {
  int idx = blockIdx.x * 256 + threadIdx.x;   // 128 blocks * 256 = 32768
  int b = idx >> 9, t = idx & 511;
  xT[t * BATCH + b] = x[idx];
}

// ---------- pass 1: layer-1 recurrence, both directions ----------
// grid = 64 blocks (dir = blk>>5, wg = blk&31), 256 threads.
// WG owns h-slice j0..j0+16; weights (4 gates x 16 rows x K=512) f16 in LDS,
// pre-swizzled to MFMA B-frag order -> per-step ds_read_b128 conflict-free.
__global__ __launch_bounds__(256) void lstm_l1(
    const float* __restrict__ whh_f, const float* __restrict__ whh_b,
    const float* __restrict__ wih_f, const float* __restrict__ wih_b,
    const float* __restrict__ bi_f,  const float* __restrict__ bh_f,
    const float* __restrict__ bi_b,  const float* __restrict__ bh_b,
    const float* __restrict__ xT,
    f16* __restrict__ C1, f16* __restrict__ hbuf, unsigned* __restrict__ ctr)
{
  __shared__ f16 wlds[4 * 16 * 64 * 8];   // 64 KB
  const int dir = blockIdx.x >> 5, wg = blockIdx.x & 31, j0 = wg * 16;
  const float* whh = dir ? whh_b : whh_f;
  const float* wih = dir ? wih_b : wih_f;
  const float* bi  = dir ? bi_b  : bi_f;
  const float* bh  = dir ? bh_b  : bh_f;
  const int tid = threadIdx.x;

  // one-time load + swizzle of weight slice into B-frag order
  for (int idx = tid; idx < 4 * 16 * 64; idx += 256) {
    const int g = idx >> 10, kk = (idx >> 6) & 15, L = idx & 63;
    const int r = L & 15, q = L >> 4;
    const float* src = whh + (size_t)(g * 512 + j0 + r) * HID + kk * 32 + q * 8;
    f16* dst = wlds + idx * 8;
#pragma unroll
    for (int j = 0; j < 8; ++j) dst[j] = (f16)src[j];
  }

  const int lane = tid & 63, wave = tid >> 6;
  const int col = lane & 15, quad = lane >> 4;
  const int m0 = wave * 16, b0 = m0 + quad * 4, jglob = j0 + col;

  float bias[4], wx[4];
#pragma unroll
  for (int g = 0; g < 4; ++g) {
    const int row = g * 512 + jglob;
    bias[g] = bi[row] + bh[row];
    wx[g]   = wih[row];          // w_ih1 is [4H][1]
  }
  float cst[4] = {0.f, 0.f, 0.f, 0.f};   // fp32 cell state, register-resident

  f16* C1d = C1 + (size_t)dir * T_LEN * BATCH * HID;
  f16* hb  = hbuf + (size_t)dir * 2 * BATCH * HID;
  unsigned* ct = ctr + dir * T_LEN;
  __syncthreads();

  for (int t = 0; t < T_LEN; ++t) {
    const f16* hA = hb + (t & 1) * BATCH * HID;
    f16*       hN = hb + ((t + 1) & 1) * BATCH * HID;
    f32x4 acc[4];
#pragma unroll
    for (int g = 0; g < 4; ++g) acc[g] = (f32x4){0.f, 0.f, 0.f, 0.f};

    const f16* aptr = hA + (size_t)(m0 + col) * HID + quad * 8;
#pragma unroll
    for (int kk = 0; kk < 16; ++kk) {
      f16x8 a = *(const f16x8*)(aptr + kk * 32);
#pragma unroll
      for (int g = 0; g < 4; ++g) {
        f16x8 b = *(const f16x8*)(wlds + ((g * 16 + kk) * 64 + lane) * 8);
        acc[g] = __builtin_amdgcn_mfma_f32_16x16x32_f16(a, b, acc[g], 0, 0, 0);
      }
    }

    const int teff = dir ? (T_LEN - 1 - t) : t;
    const float4 xv = *(const float4*)(xT + teff * BATCH + b0);
    const float xa[4] = {xv.x, xv.y, xv.z, xv.w};
    f16* c1row = C1d + (size_t)t * BATCH * HID;
#pragma unroll
    for (int r = 0; r < 4; ++r) {
      const float gi = sigm(acc[0][r] + wx[0] * xa[r] + bias[0]);
      const float gf = sigm(acc[1][r] + wx[1] * xa[r] + bias[1]);
      const float gg = tanh_f(acc[2][r] + wx[2] * xa[r] + bias[2]);
      const float go = sigm(acc[3][r] + wx[3] * xa[r] + bias[3]);
      const float c = gf * cst[r] + gi * gg;
      cst[r] = c;
      const float h = go * tanh_f(c);
      const int b = b0 + r;
      c1row[(size_t)b * HID + jglob] = (f16)c;
      hN[(size_t)b * HID + jglob]    = (f16)h;
    }
    wg_barrier(&ct[t], 32u);
  }
}

// ---------- pass 2: layer-2 recurrence (input = c1), both directions ----------
// grid = 128 blocks (dir = blk>>6, wg = blk&63), K = 1024 = [c1 | h2].
// N-tile0 rows = (i,f) x 8 j ; N-tile1 rows = (g,o) x 8 j ; pair lanes via shfl_xor 8.
__global__ __launch_bounds__(256) void lstm_l2(
    const float* __restrict__ wih_f, const float* __restrict__ whh_f,
    const float* __restrict__ wih_b, const float* __restrict__ whh_b,
    const float* __restrict__ bi_f,  const float* __restrict__ bh_f,
    const float* __restrict__ bi_b,  const float* __restrict__ bh_b,
    const f16* __restrict__ C1, f16* __restrict__ Y,
    f16* __restrict__ hbuf, unsigned* __restrict__ ctr)
{
  __shared__ f16 wlds[2 * 32 * 64 * 8];   // 64 KB
  const int dir = blockIdx.x >> 6, wg = blockIdx.x & 63, j0 = wg * 8;
  const float* wih = dir ? wih_b : wih_f;
  const float* whh = dir ? whh_b : whh_f;
  const float* bi  = dir ? bi_b  : bi_f;
  const float* bh  = dir ? bh_b  : bh_f;
  const int tid = threadIdx.x;

  for (int idx = tid; idx < 2 * 32 * 64; idx += 256) {
    const int n = idx >> 11, kk = (idx >> 6) & 31, L = idx & 63;
    const int r = L & 15, q = L >> 4;
    const int row32 = n * 16 + r;                       // 0..31 within WG
    const int grow = (row32 >> 3) * 512 + j0 + (row32 & 7);
    const int k = kk * 32 + q * 8;
    const float* src = (k < 512) ? (wih + (size_t)grow * HID + k)
                                 : (whh + (size_t)grow * HID + (k - 512));
    f16* dst = wlds + idx * 8;
#pragma unroll
    for (int j = 0; j < 8; ++j) dst[j] = (f16)src[j];
  }

  const int lane = tid & 63, wave = tid >> 6;
  const int col = lane & 15, quad = lane >> 4;
  const int m0 = wave * 16, b0 = m0 + quad * 4;
  const bool low = (col < 8);
  const int jglob = j0 + (col & 7);
  const int g0 = col >> 3;                              // tile0: 0=i, 1=f
  float bias0, bias1;
  {
    const int r0 = g0 * 512 + jglob;       bias0 = bi[r0] + bh[r0];
    const int r1 = (2 + g0) * 512 + jglob; bias1 = bi[r1] + bh[r1];
  }
  float cst[4] = {0.f, 0.f, 0.f, 0.f};

  const f16* C1d = C1 + (size_t)dir * T_LEN * BATCH * HID;
  f16* Yd = Y + (size_t)dir * T_LEN * BATCH * HID;
  f16* hb = hbuf + (size_t)dir * 2 * BATCH * HID;
  unsigned* ct = ctr + dir * T_LEN;
  __syncthreads();

  for (int t = 0; t < T_LEN; ++t) {
    const f16* c1t = C1d + (size_t)t * BATCH * HID;
    const f16* hA = hb + (t & 1) * BATCH * HID;
    f16*       hN = hb + ((t + 1) & 1) * BATCH * HID;
    f32x4 acc0 = {0.f, 0.f, 0.f, 0.f}, acc1 = {0.f, 0.f, 0.f, 0.f};
#pragma unroll
    for (int kk = 0; kk < 32; ++kk) {
      const f16* abase = (kk < 16) ? c1t : hA;
      const int koff = (kk & 15) * 32 + quad * 8;
      f16x8 a = *(const f16x8*)(abase + (size_t)(m0 + col) * HID + koff);
      f16x8 bv0 = *(const f16x8*)(wlds + ((0 * 32 + kk) * 64 + lane) * 8);
      acc0 = __builtin_amdgcn_mfma_f32_16x16x32_f16(a, bv0, acc0, 0, 0, 0);
      f16x8 bv1 = *(const f16x8*)(wlds + ((1 * 32 + kk) * 64 + lane) * 8);
      acc1 = __builtin_amdgcn_mfma_f32_16x16x32_f16(a, bv1, acc1, 0, 0, 0);
    }
    f16* yrow = Yd + (size_t)t * BATCH * HID;
#pragma unroll
    for (int r = 0; r < 4; ++r) {
      const float v0 = acc0[r] + bias0;                 // low: pre_i, high: pre_f
      const float v1 = acc1[r] + bias1;                 // low: pre_g, high: pre_o
      const float sa = sigm(v0);
      const float sb = low ? tanh_f(v1) : sigm(v1);
      const float prod = sa * sb;                       // low: i*tanh(g)
      const float recv = __shfl_xor(prod, 8, 64);
      if (!low) {
        const float c = sa * cst[r] + recv;             // f*c + i*tanh(g)
        cst[r] = c;
        const float h = sb * tanh_f(c);                 // o*tanh(c)
        const int b = b0 + r;
        yrow[(size_t)b * HID + jglob] = (f16)c;         // output is c2
        hN[(size_t)b * HID + jglob]   = (f16)h;
      }
    }
    wg_barrier(&ct[t], 64u);
  }
}

// ---------- pass 3: output FC, both directions ----------
// grid = 1024 blocks (dir = blk>>9, t = blk&511), 256 threads.
__global__ __launch_bounds__(256) void fc_out(
    const f16* __restrict__ Y,
    const float* __restrict__ fw, const float* __restrict__ fb,
    const float* __restrict__ bw, const float* __restrict__ bb,
    float* __restrict__ out)
{
  const int dir = blockIdx.x >> 9;
  const int t = blockIdx.x & 511;
  const int tid = threadIdx.x;
  const int b = tid & 63;
  const int c0 = (tid >> 6) * 16;
  const float* W  = dir ? bw : fw;
  const float* Bv = dir ? bb : fb;
  const f16* yrow = Y + ((size_t)(dir * T_LEN + t) * BATCH + b) * HID;

  float acc[16];
#pragma unroll
  for (int c = 0; c < 16; ++c) acc[c] = 0.f;

  for (int k = 0; k < HID; k += 8) {
    f16x8 yv = *(const f16x8*)(yrow + k);
    float yf[8];
#pragma unroll
    for (int j = 0; j < 8; ++j) yf[j] = (float)yv[j];
#pragma unroll
    for (int c = 0; c < 16; ++c) {
      const float* wr = W + (size_t)(c0 + c) * HID + k;
      const float4 w0 = *(const float4*)wr;
      const float4 w1 = *(const float4*)(wr + 4);
      acc[c] += yf[0] * w0.x + yf[1] * w0.y + yf[2] * w0.z + yf[3] * w0.w
              + yf[4] * w1.x + yf[5] * w1.y + yf[6] * w1.z + yf[7] * w1.w;
    }
  }
  float* orow = out + (size_t)dir * (BATCH * T_LEN * 64)
                    + ((size_t)b * T_LEN + t) * 64 + c0;
#pragma unroll
  for (int c = 0; c < 16; ++c) orow[c] = acc[c] + Bv[c0 + c];
}

// ---------- launch ----------
extern "C" void kernel_launch(void* const* d_in, const int* in_sizes, int n_in,
                              void* d_out, int out_size, void* d_ws, size_t ws_size,
                              hipStream_t stream) {
  const float* x     = (const float*)d_in[0];
  const float* w_ih1 = (const float*)d_in[1];
  const float* w_hh1 = (const float*)d_in[2];
  const float* b_ih1 = (const float*)d_in[3];
  const float* b_hh1 = (const float*)d_in[4];
  const float* w_ih2 = (const float*)d_in[5];
  const float* w_hh2 = (const float*)d_in[6];
  const float* b_ih2 = (const float*)d_in[7];
  const float* b_hh2 = (const float*)d_in[8];
  const float* w_ih3 = (const float*)d_in[9];
  const float* w_hh3 = (const float*)d_in[10];
  const float* b_ih3 = (const float*)d_in[11];
  const float* b_hh3 = (const float*)d_in[12];
  const float* w_ih4 = (const float*)d_in[13];
  const float* w_hh4 = (const float*)d_in[14];
  const float* b_ih4 = (const float*)d_in[15];
  const float* b_hh4 = (const float*)d_in[16];
  const float* fc_w  = (const float*)d_in[17];
  const float* fc_b  = (const float*)d_in[18];
  const float* bfc_w = (const float*)d_in[19];
  const float* bfc_b = (const float*)d_in[20];

  // ws layout (bytes)
  const size_t SEQ_BYTES = (size_t)2 * T_LEN * BATCH * HID * sizeof(f16); // 64 MB
  char* ws = (char*)d_ws;
  f16* C1   = (f16*)(ws);                         // [2][T][B][H]
  f16* Yb   = (f16*)(ws + SEQ_BYTES);             // [2][T][B][H]
  char* st  = ws + 2 * SEQ_BYTES;
  f16* h1b  = (f16*)(st);                         // [2][2][B][H]
  f16* h2b  = (f16*)(st + 262144);                // [2][2][B][H]
  unsigned* ctr1 = (unsigned*)(st + 524288);      // [2][T]
  unsigned* ctr2 = (unsigned*)(st + 524288 + 4096);
  float* xT = (float*)(st + 524288 + 8192);       // [T][B]

  // zero h-state buffers + step counters (ws is poisoned 0xAA each launch)
  hipMemsetAsync(st, 0, 524288 + 8192, stream);

  xpose<<<128, 256, 0, stream>>>(x, xT);
  lstm_l1<<<64, 256, 0, stream>>>(w_hh1, w_hh3, w_ih1, w_ih3,
                                  b_ih1, b_hh1, b_ih3, b_hh3,
                                  xT, C1, h1b, ctr1);
  lstm_l2<<<128, 256, 0, stream>>>(w_ih2, w_hh2, w_ih4, w_hh4,
                                   b_ih2, b_hh2, b_ih4, b_hh4,
                                   C1, Yb, h2b, ctr2);
  fc_out<<<1024, 256, 0, stream>>>(Yb, fc_w, fc_b, bfc_w, bfc_b, (float*)d_out);
}

// Round 3
// 7170.052 us; speedup vs baseline: 1.4195x; 1.4195x over previous
//
#include <hip/hip_runtime.h>

typedef _Float16 f16;
typedef f16   f16x8 __attribute__((ext_vector_type(8)));
typedef float f32x4 __attribute__((ext_vector_type(4)));

#define T_LEN 512
#define BATCH 64
#define HID   512

__device__ __forceinline__ float sigm(float x) { return 1.0f / (1.0f + __expf(-x)); }
__device__ __forceinline__ float tanh_f(float x) {
  x = fminf(fmaxf(x, -15.0f), 15.0f);
  float e = __expf(2.0f * x);
  return (e - 1.0f) / (e + 1.0f);
}

// Two-level barrier, monotonic counters (no per-step arrays, no re-zeroing).
// 12 groups x 8 WGs arrive on 12 separate 128B-padded lines (parallel), group
// winner bumps the root line (12 serialized RMWs), everyone spins on root.
// Release/acquire agent fences exactly as the proven round-1 barrier.
__device__ __forceinline__ void tree_barrier(unsigned* grp, unsigned* root,
                                             int mygrp, unsigned s) {
  __syncthreads();                      // all this WG's stores issued
  if (threadIdx.x == 0) {
    __builtin_amdgcn_fence(__ATOMIC_RELEASE, "agent");   // push dirty lines (wbL2)
    unsigned old = __hip_atomic_fetch_add(grp + mygrp * 32, 1u,
                       __ATOMIC_RELAXED, __HIP_MEMORY_SCOPE_AGENT);
    if (old == 8u * (s + 1u) - 1u)      // last of my 8-WG group this step
      __hip_atomic_fetch_add(root, 1u, __ATOMIC_RELAXED, __HIP_MEMORY_SCOPE_AGENT);
    while (__hip_atomic_load(root, __ATOMIC_RELAXED, __HIP_MEMORY_SCOPE_AGENT)
           < 12u * (s + 1u)) {
      __builtin_amdgcn_s_sleep(1);      // back off ~64 cyc: don't hammer root line
    }
    __builtin_amdgcn_fence(__ATOMIC_ACQUIRE, "agent");   // inv L1/L2 before re-reads
  }
  __syncthreads();
}

// Fused skewed recurrence. Blocks 0..63: layer-1 (t = s). Blocks 64..191:
// layer-2 (t = s-1). Per dir: 32 l1-WGs + 64 l2-WGs = 96 share one barrier
// per step; 513 skewed steps replace 1024 serial steps.
__global__ __launch_bounds__(256) void lstm_fused(
    const float* __restrict__ w_ih1, const float* __restrict__ w_hh1,
    const float* __restrict__ b_ih1, const float* __restrict__ b_hh1,
    const float* __restrict__ w_ih2, const float* __restrict__ w_hh2,
    const float* __restrict__ b_ih2, const float* __restrict__ b_hh2,
    const float* __restrict__ w_ih3, const float* __restrict__ w_hh3,
    const float* __restrict__ b_ih3, const float* __restrict__ b_hh3,
    const float* __restrict__ w_ih4, const float* __restrict__ w_hh4,
    const float* __restrict__ b_ih4, const float* __restrict__ b_hh4,
    const float* __restrict__ x,
    f16* __restrict__ C1, f16* __restrict__ Y,
    f16* __restrict__ h1buf, f16* __restrict__ h2buf,
    unsigned* __restrict__ grpc, unsigned* __restrict__ rootc)
{
  __shared__ f16 wlds[32768];   // 64 KB, role-specific layout
  const int tid = threadIdx.x;
  const int lane = tid & 63, wave = tid >> 6;
  const int col = lane & 15, quad = lane >> 4;
  const int m0 = wave * 16, b0 = m0 + quad * 4;

  if (blockIdx.x < 64) {
    // ---------------- layer-1 role ----------------
    const int dir = blockIdx.x >> 5, wg = blockIdx.x & 31, j0 = wg * 16;
    const float* whh = dir ? w_hh3 : w_hh1;
    const float* wih = dir ? w_ih3 : w_ih1;
    const float* bi  = dir ? b_ih3 : b_ih1;
    const float* bh  = dir ? b_hh3 : b_hh1;
    unsigned* grp  = grpc + dir * 12 * 32;
    unsigned* root = rootc + dir * 32;
    const int mygrp = wg >> 3;           // groups 0..3

    // one-time load + swizzle of weight slice into MFMA B-frag order
    for (int idx = tid; idx < 4 * 16 * 64; idx += 256) {
      const int g = idx >> 10, kk = (idx >> 6) & 15, L = idx & 63;
      const int r = L & 15, q = L >> 4;
      const float* src = whh + (size_t)(g * 512 + j0 + r) * HID + kk * 32 + q * 8;
      f16* dst = wlds + idx * 8;
#pragma unroll
      for (int j = 0; j < 8; ++j) dst[j] = (f16)src[j];
    }

    const int jglob = j0 + col;
    float bias[4], wx[4];
#pragma unroll
    for (int g = 0; g < 4; ++g) {
      const int row = g * 512 + jglob;
      bias[g] = bi[row] + bh[row];
      wx[g]   = wih[row];               // w_ih is [4H][1]
    }
    float cst[4] = {0.f, 0.f, 0.f, 0.f};   // fp32 cell state, register-resident

    f16* C1d = C1 + (size_t)dir * T_LEN * BATCH * HID;
    f16* hb  = h1buf + (size_t)dir * 2 * BATCH * HID;
    __syncthreads();

    for (int t = 0; t < T_LEN; ++t) {
      const f16* hA = hb + (t & 1) * BATCH * HID;
      f16*       hN = hb + ((t + 1) & 1) * BATCH * HID;
      f32x4 acc[4];
#pragma unroll
      for (int g = 0; g < 4; ++g) acc[g] = (f32x4){0.f, 0.f, 0.f, 0.f};

      const f16* aptr = hA + (size_t)(m0 + col) * HID + quad * 8;
#pragma unroll
      for (int kk = 0; kk < 16; ++kk) {
        f16x8 a = *(const f16x8*)(aptr + kk * 32);
#pragma unroll
        for (int g = 0; g < 4; ++g) {
          f16x8 b = *(const f16x8*)(wlds + ((g * 16 + kk) * 64 + lane) * 8);
          acc[g] = __builtin_amdgcn_mfma_f32_16x16x32_f16(a, b, acc[g], 0, 0, 0);
        }
      }

      const int teff = dir ? (T_LEN - 1 - t) : t;
      f16* c1row = C1d + (size_t)t * BATCH * HID;
#pragma unroll
      for (int r = 0; r < 4; ++r) {
        const float xv = x[(size_t)(b0 + r) * T_LEN + teff];
        const float gi = sigm(acc[0][r] + wx[0] * xv + bias[0]);
        const float gf = sigm(acc[1][r] + wx[1] * xv + bias[1]);
        const float gg = tanh_f(acc[2][r] + wx[2] * xv + bias[2]);
        const float go = sigm(acc[3][r] + wx[3] * xv + bias[3]);
        const float c = gf * cst[r] + gi * gg;
        cst[r] = c;
        const float h = go * tanh_f(c);
        const int b = b0 + r;
        c1row[(size_t)b * HID + jglob] = (f16)c;
        hN[(size_t)b * HID + jglob]    = (f16)h;
      }
      tree_barrier(grp, root, mygrp, (unsigned)t);
    }
  } else {
    // ---------------- layer-2 role ----------------
    const int bb = blockIdx.x - 64;
    const int dir = bb >> 6, wg = bb & 63, j0 = wg * 8;
    const float* wih = dir ? w_ih4 : w_ih2;
    const float* whh = dir ? w_hh4 : w_hh2;
    const float* bi  = dir ? b_ih4 : b_ih2;
    const float* bh  = dir ? b_hh4 : b_hh2;
    unsigned* grp  = grpc + dir * 12 * 32;
    unsigned* root = rootc + dir * 32;
    const int mygrp = (32 + wg) >> 3;    // groups 4..11

    for (int idx = tid; idx < 2 * 32 * 64; idx += 256) {
      const int n = idx >> 11, kk = (idx >> 6) & 31, L = idx & 63;
      const int r = L & 15, q = L >> 4;
      const int row32 = n * 16 + r;
      const int grow = (row32 >> 3) * 512 + j0 + (row32 & 7);
      const int k = kk * 32 + q * 8;
      const float* src = (k < 512) ? (wih + (size_t)grow * HID + k)
                                   : (whh + (size_t)grow * HID + (k - 512));
      f16* dst = wlds + idx * 8;
#pragma unroll
      for (int j = 0; j < 8; ++j) dst[j] = (f16)src[j];
    }

    const bool low = (col < 8);
    const int jglob = j0 + (col & 7);
    const int g0 = col >> 3;             // tile0 rows: 0=i, 1=f (tile1: g, o)
    float bias0, bias1;
    {
      const int r0 = g0 * 512 + jglob;       bias0 = bi[r0] + bh[r0];
      const int r1 = (2 + g0) * 512 + jglob; bias1 = bi[r1] + bh[r1];
    }
    float cst[4] = {0.f, 0.f, 0.f, 0.f};

    const f16* C1d = C1 + (size_t)dir * T_LEN * BATCH * HID;
    f16* Yd = Y + (size_t)dir * T_LEN * BATCH * HID;
    f16* hb = h2buf + (size_t)dir * 2 * BATCH * HID;
    __syncthreads();

    for (int s = 0; s < 513; ++s) {
      if (s >= 1) {
        const int t = s - 1;
        const f16* c1t = C1d + (size_t)t * BATCH * HID;
        const f16* hA = hb + (t & 1) * BATCH * HID;
        f16*       hN = hb + ((t + 1) & 1) * BATCH * HID;
        f32x4 acc0 = {0.f, 0.f, 0.f, 0.f}, acc1 = {0.f, 0.f, 0.f, 0.f};
#pragma unroll
        for (int kk = 0; kk < 32; ++kk) {
          const f16* abase = (kk < 16) ? c1t : hA;
          const int koff = (kk & 15) * 32 + quad * 8;
          f16x8 a = *(const f16x8*)(abase + (size_t)(m0 + col) * HID + koff);
          f16x8 bv0 = *(const f16x8*)(wlds + ((0 * 32 + kk) * 64 + lane) * 8);
          acc0 = __builtin_amdgcn_mfma_f32_16x16x32_f16(a, bv0, acc0, 0, 0, 0);
          f16x8 bv1 = *(const f16x8*)(wlds + ((1 * 32 + kk) * 64 + lane) * 8);
          acc1 = __builtin_amdgcn_mfma_f32_16x16x32_f16(a, bv1, acc1, 0, 0, 0);
        }
        f16* yrow = Yd + (size_t)t * BATCH * HID;
#pragma unroll
        for (int r = 0; r < 4; ++r) {
          const float v0 = acc0[r] + bias0;   // low: pre_i, high: pre_f
          const float v1 = acc1[r] + bias1;   // low: pre_g, high: pre_o
          const float sa = sigm(v0);
          const float sb = low ? tanh_f(v1) : sigm(v1);
          const float prod = sa * sb;         // low lanes: i*tanh(g)
          const float recv = __shfl_xor(prod, 8, 64);
          if (!low) {
            const float c = sa * cst[r] + recv;   // f*c + i*tanh(g)
            cst[r] = c;
            const float h = sb * tanh_f(c);       // o*tanh(c)
            const int b = b0 + r;
            yrow[(size_t)b * HID + jglob] = (f16)c;  // output is c2
            hN[(size_t)b * HID + jglob]   = (f16)h;
          }
        }
      }
      if (s < 512) tree_barrier(grp, root, mygrp, (unsigned)s);
    }
  }
}

// ---------- output FC, both directions ----------
__global__ __launch_bounds__(256) void fc_out(
    const f16* __restrict__ Y,
    const float* __restrict__ fw, const float* __restrict__ fb,
    const float* __restrict__ bw, const float* __restrict__ bb,
    float* __restrict__ out)
{
  const int dir = blockIdx.x >> 9;
  const int t = blockIdx.x & 511;
  const int tid = threadIdx.x;
  const int b = tid & 63;
  const int c0 = (tid >> 6) * 16;
  const float* W  = dir ? bw : fw;
  const float* Bv = dir ? bb : fb;
  const f16* yrow = Y + ((size_t)(dir * T_LEN + t) * BATCH + b) * HID;

  float acc[16];
#pragma unroll
  for (int c = 0; c < 16; ++c) acc[c] = 0.f;

  for (int k = 0; k < HID; k += 8) {
    f16x8 yv = *(const f16x8*)(yrow + k);
    float yf[8];
#pragma unroll
    for (int j = 0; j < 8; ++j) yf[j] = (float)yv[j];
#pragma unroll
    for (int c = 0; c < 16; ++c) {
      const float* wr = W + (size_t)(c0 + c) * HID + k;
      const float4 w0 = *(const float4*)wr;
      const float4 w1 = *(const float4*)(wr + 4);
      acc[c] += yf[0] * w0.x + yf[1] * w0.y + yf[2] * w0.z + yf[3] * w0.w
              + yf[4] * w1.x + yf[5] * w1.y + yf[6] * w1.z + yf[7] * w1.w;
    }
  }
  float* orow = out + (size_t)dir * (BATCH * T_LEN * 64)
                    + ((size_t)b * T_LEN + t) * 64 + c0;
#pragma unroll
  for (int c = 0; c < 16; ++c) orow[c] = acc[c] + Bv[c0 + c];
}

// ---------- launch ----------
extern "C" void kernel_launch(void* const* d_in, const int* in_sizes, int n_in,
                              void* d_out, int out_size, void* d_ws, size_t ws_size,
                              hipStream_t stream) {
  const float* x     = (const float*)d_in[0];
  const float* w_ih1 = (const float*)d_in[1];
  const float* w_hh1 = (const float*)d_in[2];
  const float* b_ih1 = (const float*)d_in[3];
  const float* b_hh1 = (const float*)d_in[4];
  const float* w_ih2 = (const float*)d_in[5];
  const float* w_hh2 = (const float*)d_in[6];
  const float* b_ih2 = (const float*)d_in[7];
  const float* b_hh2 = (const float*)d_in[8];
  const float* w_ih3 = (const float*)d_in[9];
  const float* w_hh3 = (const float*)d_in[10];
  const float* b_ih3 = (const float*)d_in[11];
  const float* b_hh3 = (const float*)d_in[12];
  const float* w_ih4 = (const float*)d_in[13];
  const float* w_hh4 = (const float*)d_in[14];
  const float* b_ih4 = (const float*)d_in[15];
  const float* b_hh4 = (const float*)d_in[16];
  const float* fc_w  = (const float*)d_in[17];
  const float* fc_b  = (const float*)d_in[18];
  const float* bfc_w = (const float*)d_in[19];
  const float* bfc_b = (const float*)d_in[20];

  // ws layout (bytes):
  //   [h1 256KB][h2 256KB][grp 3KB][root 256B][pad][C1 64MB][Y 64MB]
  char* ws = (char*)d_ws;
  f16* h1b = (f16*)(ws);
  f16* h2b = (f16*)(ws + 262144);
  unsigned* grpc  = (unsigned*)(ws + 524288);   // [2 dirs][12 grp][32 pad]
  unsigned* rootc = (unsigned*)(ws + 527360);   // [2 dirs][32 pad]
  const size_t SEQ_BYTES = (size_t)2 * T_LEN * BATCH * HID * sizeof(f16); // 64 MB
  f16* C1 = (f16*)(ws + 532480);
  f16* Yb = (f16*)(ws + 532480 + SEQ_BYTES);

  // zero h-state buffers + barrier counters (ws is poisoned 0xAA each launch)
  hipMemsetAsync(ws, 0, 532480, stream);

  lstm_fused<<<192, 256, 0, stream>>>(
      w_ih1, w_hh1, b_ih1, b_hh1, w_ih2, w_hh2, b_ih2, b_hh2,
      w_ih3, w_hh3, b_ih3, b_hh3, w_ih4, w_hh4, b_ih4, b_hh4,
      x, C1, Yb, h1b, h2b, grpc, rootc);
  fc_out<<<1024, 256, 0, stream>>>(Yb, fc_w, fc_b, bfc_w, bfc_b, (float*)d_out);
}

// Round 4
// 5430.896 us; speedup vs baseline: 1.8741x; 1.3202x over previous
//
#include <hip/hip_runtime.h>

typedef _Float16 f16;
typedef f16   f16x8 __attribute__((ext_vector_type(8)));
typedef float f32x4 __attribute__((ext_vector_type(4)));

#define T_LEN 512
#define BATCH 64
#define HID   512

__device__ __forceinline__ float sigm(float x) { return 1.0f / (1.0f + __expf(-x)); }
__device__ __forceinline__ float tanh_f(float x) {
  x = fminf(fmaxf(x, -15.0f), 15.0f);
  float e = __expf(2.0f * x);
  return (e - 1.0f) / (e + 1.0f);
}

// write-through coherent 2B store: visible at coherence point (L3) once vmcnt
// retires -> release needs only a vmcnt drain, no buffer_wbl2.
__device__ __forceinline__ void st_coh16(f16* p, f16 v) {
  unsigned int b = (unsigned int)__builtin_bit_cast(unsigned short, v);
  asm volatile("global_store_short %0, %1, off sc0 sc1" :: "v"(p), "v"(b) : "memory");
}

// Two-level barrier, monotonic counters. 6 groups x 8 WGs per direction.
// Release side: all communicated stores are sc0/sc1 write-through, so a
// vmcnt(0) drain (in ALL threads, before syncthreads) + relaxed atomic is a
// release. Acquire side keeps the agent fence (buffer_inv) so plain cached
// vector loads refetch fresh data.
__device__ __forceinline__ void tree_barrier(unsigned* grp, unsigned* root,
                                             int mygrp, unsigned s) {
  asm volatile("s_waitcnt vmcnt(0)" ::: "memory");   // drain my wave's stores
  __syncthreads();
  if (threadIdx.x == 0) {
    unsigned old = __hip_atomic_fetch_add(grp + mygrp * 32, 1u,
                       __ATOMIC_RELAXED, __HIP_MEMORY_SCOPE_AGENT);
    if (old == 8u * (s + 1u) - 1u)      // last of my 8-WG group this step
      __hip_atomic_fetch_add(root, 1u, __ATOMIC_RELAXED, __HIP_MEMORY_SCOPE_AGENT);
    while (__hip_atomic_load(root, __ATOMIC_RELAXED, __HIP_MEMORY_SCOPE_AGENT)
           < 6u * (s + 1u)) {
      __builtin_amdgcn_s_sleep(1);      // back off: don't hammer the root line
    }
    __builtin_amdgcn_fence(__ATOMIC_ACQUIRE, "agent");   // inv L1/L2 before re-reads
  }
  __syncthreads();
}

// Fused skewed recurrence, 96 blocks (1 WG/CU; LDS 128 KB dynamic):
//   blocks 0..31 : layer-1, 16 WGs/dir x 32 cols, t = s
//   blocks 32..95: layer-2, 32 WGs/dir x 16 cols, t = s-1
// Per direction 48 WGs share one tree barrier per step; 513 skewed steps.
__global__ __launch_bounds__(256) void lstm_fused(
    const float* __restrict__ w_ih1, const float* __restrict__ w_hh1,
    const float* __restrict__ b_ih1, const float* __restrict__ b_hh1,
    const float* __restrict__ w_ih2, const float* __restrict__ w_hh2,
    const float* __restrict__ b_ih2, const float* __restrict__ b_hh2,
    const float* __restrict__ w_ih3, const float* __restrict__ w_hh3,
    const float* __restrict__ b_ih3, const float* __restrict__ b_hh3,
    const float* __restrict__ w_ih4, const float* __restrict__ w_hh4,
    const float* __restrict__ b_ih4, const float* __restrict__ b_hh4,
    const float* __restrict__ x,
    f16* __restrict__ C1, f16* __restrict__ Y,
    f16* __restrict__ h1buf, f16* __restrict__ h2buf,
    unsigned* __restrict__ grpc, unsigned* __restrict__ rootc)
{
  extern __shared__ f16 wlds[];         // 128 KB dynamic
  const int tid = threadIdx.x;
  const int lane = tid & 63, wave = tid >> 6;
  const int col = lane & 15, quad = lane >> 4;
  const int m0 = wave * 16, b0 = m0 + quad * 4;

  if (blockIdx.x < 32) {
    // ---------------- layer-1 role: 32 cols, K=512, 8 N-tiles ----------------
    const int dir = blockIdx.x >> 4, wg = blockIdx.x & 15, j0 = wg * 32;
    const float* whh = dir ? w_hh3 : w_hh1;
    const float* wih = dir ? w_ih3 : w_ih1;
    const float* bi  = dir ? b_ih3 : b_ih1;
    const float* bh  = dir ? b_hh3 : b_hh1;
    unsigned* grp  = grpc + dir * 6 * 32;
    unsigned* root = rootc + dir * 32;
    const int mygrp = wg >> 3;           // groups 0..1

    // stage weights into MFMA B-frag order; tile n: gate g=n&3, half=n>>2
    for (int idx = tid; idx < 8 * 16 * 64; idx += 256) {
      const int n = idx >> 10, kk = (idx >> 6) & 15, L = idx & 63;
      const int r = L & 15, q = L >> 4;
      const int g = n & 3, half = n >> 2;
      const float* src = whh + (size_t)(g * 512 + j0 + half * 16 + r) * HID
                             + kk * 32 + q * 8;
      f16* dst = wlds + idx * 8;
#pragma unroll
      for (int j = 0; j < 8; ++j) dst[j] = (f16)src[j];
    }

    float bias[2][4], wx[2][4];
#pragma unroll
    for (int half = 0; half < 2; ++half)
#pragma unroll
      for (int g = 0; g < 4; ++g) {
        const int row = g * 512 + j0 + half * 16 + col;
        bias[half][g] = bi[row] + bh[row];
        wx[half][g]   = wih[row];        // w_ih is [4H][1]
      }
    float cst[2][4] = {{0.f,0.f,0.f,0.f},{0.f,0.f,0.f,0.f}};

    f16* C1d = C1 + (size_t)dir * T_LEN * BATCH * HID;
    f16* hb  = h1buf + (size_t)dir * 2 * BATCH * HID;
    __syncthreads();

    for (int t = 0; t < T_LEN; ++t) {
      const f16* hA = hb + (t & 1) * BATCH * HID;
      f16*       hN = hb + ((t + 1) & 1) * BATCH * HID;
      f32x4 acc[8];
#pragma unroll
      for (int n = 0; n < 8; ++n) acc[n] = (f32x4){0.f, 0.f, 0.f, 0.f};

      const f16* aptr = hA + (size_t)(m0 + col) * HID + quad * 8;
      f16x8 a[16];
#pragma unroll
      for (int kk = 0; kk < 16; ++kk) a[kk] = *(const f16x8*)(aptr + kk * 32);
#pragma unroll
      for (int kk = 0; kk < 16; ++kk) {
#pragma unroll
        for (int n = 0; n < 8; ++n) {
          f16x8 b = *(const f16x8*)(wlds + ((n * 16 + kk) * 64 + lane) * 8);
          acc[n] = __builtin_amdgcn_mfma_f32_16x16x32_f16(a[kk], b, acc[n], 0, 0, 0);
        }
      }

      const int teff = dir ? (T_LEN - 1 - t) : t;
      f16* c1row = C1d + (size_t)t * BATCH * HID;
#pragma unroll
      for (int half = 0; half < 2; ++half) {
        const int jg = j0 + half * 16 + col;
#pragma unroll
        for (int r = 0; r < 4; ++r) {
          const float xv = x[(size_t)(b0 + r) * T_LEN + teff];
          const float gi = sigm(acc[0 + half * 4][r] + wx[half][0] * xv + bias[half][0]);
          const float gf = sigm(acc[1 + half * 4][r] + wx[half][1] * xv + bias[half][1]);
          const float gg = tanh_f(acc[2 + half * 4][r] + wx[half][2] * xv + bias[half][2]);
          const float go = sigm(acc[3 + half * 4][r] + wx[half][3] * xv + bias[half][3]);
          const float c = gf * cst[half][r] + gi * gg;
          cst[half][r] = c;
          const float h = go * tanh_f(c);
          const int b = b0 + r;
          st_coh16(c1row + (size_t)b * HID + jg, (f16)c);
          st_coh16(hN + (size_t)b * HID + jg, (f16)h);
        }
      }
      tree_barrier(grp, root, mygrp, (unsigned)t);
    }
  } else {
    // ---------------- layer-2 role: 16 cols, K=1024, 4 N-tiles (one/gate) ----
    const int bb = blockIdx.x - 32;
    const int dir = bb >> 5, wg = bb & 31, j0 = wg * 16;
    const float* wih = dir ? w_ih4 : w_ih2;
    const float* whh = dir ? w_hh4 : w_hh2;
    const float* bi  = dir ? b_ih4 : b_ih2;
    const float* bh  = dir ? b_hh4 : b_hh2;
    unsigned* grp  = grpc + dir * 6 * 32;
    unsigned* root = rootc + dir * 32;
    const int mygrp = 2 + (wg >> 3);     // groups 2..5

    // tile n = gate; K = [c1 (0..511) | h2 (512..1023)]
    for (int idx = tid; idx < 4 * 32 * 64; idx += 256) {
      const int n = idx >> 11, kk = (idx >> 6) & 31, L = idx & 63;
      const int r = L & 15, q = L >> 4;
      const int grow = n * 512 + j0 + r;
      const int k = kk * 32 + q * 8;
      const float* src = (k < 512) ? (wih + (size_t)grow * HID + k)
                                   : (whh + (size_t)grow * HID + (k - 512));
      f16* dst = wlds + idx * 8;
#pragma unroll
      for (int j = 0; j < 8; ++j) dst[j] = (f16)src[j];
    }

    const int jg = j0 + col;
    float bias[4];
#pragma unroll
    for (int g = 0; g < 4; ++g) bias[g] = bi[g * 512 + jg] + bh[g * 512 + jg];
    float cst[4] = {0.f, 0.f, 0.f, 0.f};

    const f16* C1d = C1 + (size_t)dir * T_LEN * BATCH * HID;
    f16* Yd = Y + (size_t)dir * T_LEN * BATCH * HID;
    f16* hb = h2buf + (size_t)dir * 2 * BATCH * HID;
    __syncthreads();

    for (int s = 0; s < 513; ++s) {
      if (s >= 1) {
        const int t = s - 1;
        const f16* c1t = C1d + (size_t)t * BATCH * HID;
        const f16* hA = hb + (t & 1) * BATCH * HID;
        f16*       hN = hb + ((t + 1) & 1) * BATCH * HID;
        const f16* aptrC = c1t + (size_t)(m0 + col) * HID + quad * 8;
        const f16* aptrH = hA  + (size_t)(m0 + col) * HID + quad * 8;
        f16x8 a[32];
#pragma unroll
        for (int kk = 0; kk < 16; ++kk) a[kk]      = *(const f16x8*)(aptrC + kk * 32);
#pragma unroll
        for (int kk = 0; kk < 16; ++kk) a[16 + kk] = *(const f16x8*)(aptrH + kk * 32);

        f32x4 acc[4];
#pragma unroll
        for (int n = 0; n < 4; ++n) acc[n] = (f32x4){0.f, 0.f, 0.f, 0.f};
#pragma unroll
        for (int kk = 0; kk < 32; ++kk) {
#pragma unroll
          for (int n = 0; n < 4; ++n) {
            f16x8 b = *(const f16x8*)(wlds + ((n * 32 + kk) * 64 + lane) * 8);
            acc[n] = __builtin_amdgcn_mfma_f32_16x16x32_f16(a[kk], b, acc[n], 0, 0, 0);
          }
        }
        f16* yrow = Yd + (size_t)t * BATCH * HID;
#pragma unroll
        for (int r = 0; r < 4; ++r) {
          const float gi = sigm(acc[0][r] + bias[0]);
          const float gf = sigm(acc[1][r] + bias[1]);
          const float gg = tanh_f(acc[2][r] + bias[2]);
          const float go = sigm(acc[3][r] + bias[3]);
          const float c = gf * cst[r] + gi * gg;
          cst[r] = c;
          const float h = go * tanh_f(c);
          const int b = b0 + r;
          yrow[(size_t)b * HID + jg] = (f16)c;   // plain: consumed post-kernel
          st_coh16(hN + (size_t)b * HID + jg, (f16)h);
        }
      }
      if (s < 512) tree_barrier(grp, root, mygrp, (unsigned)s);
    }
  }
}

// ---------- output FC, both directions ----------
__global__ __launch_bounds__(256) void fc_out(
    const f16* __restrict__ Y,
    const float* __restrict__ fw, const float* __restrict__ fb,
    const float* __restrict__ bw, const float* __restrict__ bb,
    float* __restrict__ out)
{
  const int dir = blockIdx.x >> 9;
  const int t = blockIdx.x & 511;
  const int tid = threadIdx.x;
  const int b = tid & 63;
  const int c0 = (tid >> 6) * 16;
  const float* W  = dir ? bw : fw;
  const float* Bv = dir ? bb : fb;
  const f16* yrow = Y + ((size_t)(dir * T_LEN + t) * BATCH + b) * HID;

  float acc[16];
#pragma unroll
  for (int c = 0; c < 16; ++c) acc[c] = 0.f;

  for (int k = 0; k < HID; k += 8) {
    f16x8 yv = *(const f16x8*)(yrow + k);
    float yf[8];
#pragma unroll
    for (int j = 0; j < 8; ++j) yf[j] = (float)yv[j];
#pragma unroll
    for (int c = 0; c < 16; ++c) {
      const float* wr = W + (size_t)(c0 + c) * HID + k;
      const float4 w0 = *(const float4*)wr;
      const float4 w1 = *(const float4*)(wr + 4);
      acc[c] += yf[0] * w0.x + yf[1] * w0.y + yf[2] * w0.z + yf[3] * w0.w
              + yf[4] * w1.x + yf[5] * w1.y + yf[6] * w1.z + yf[7] * w1.w;
    }
  }
  float* orow = out + (size_t)dir * (BATCH * T_LEN * 64)
                    + ((size_t)b * T_LEN + t) * 64 + c0;
#pragma unroll
  for (int c = 0; c < 16; ++c) orow[c] = acc[c] + Bv[c0 + c];
}

// ---------- launch ----------
extern "C" void kernel_launch(void* const* d_in, const int* in_sizes, int n_in,
                              void* d_out, int out_size, void* d_ws, size_t ws_size,
                              hipStream_t stream) {
  const float* x     = (const float*)d_in[0];
  const float* w_ih1 = (const float*)d_in[1];
  const float* w_hh1 = (const float*)d_in[2];
  const float* b_ih1 = (const float*)d_in[3];
  const float* b_hh1 = (const float*)d_in[4];
  const float* w_ih2 = (const float*)d_in[5];
  const float* w_hh2 = (const float*)d_in[6];
  const float* b_ih2 = (const float*)d_in[7];
  const float* b_hh2 = (const float*)d_in[8];
  const float* w_ih3 = (const float*)d_in[9];
  const float* w_hh3 = (const float*)d_in[10];
  const float* b_ih3 = (const float*)d_in[11];
  const float* b_hh3 = (const float*)d_in[12];
  const float* w_ih4 = (const float*)d_in[13];
  const float* w_hh4 = (const float*)d_in[14];
  const float* b_ih4 = (const float*)d_in[15];
  const float* b_hh4 = (const float*)d_in[16];
  const float* fc_w  = (const float*)d_in[17];
  const float* fc_b  = (const float*)d_in[18];
  const float* bfc_w = (const float*)d_in[19];
  const float* bfc_b = (const float*)d_in[20];

  // ws layout (bytes):
  //   [h1 256KB][h2 256KB][grp 1.5KB][root 256B][pad][C1 64MB][Y 64MB]
  char* ws = (char*)d_ws;
  f16* h1b = (f16*)(ws);
  f16* h2b = (f16*)(ws + 262144);
  unsigned* grpc  = (unsigned*)(ws + 524288);   // [2 dirs][6 grp][32 pad]
  unsigned* rootc = (unsigned*)(ws + 525824);   // [2 dirs][32 pad]
  const size_t SEQ_BYTES = (size_t)2 * T_LEN * BATCH * HID * sizeof(f16); // 64 MB
  f16* C1 = (f16*)(ws + 532480);
  f16* Yb = (f16*)(ws + 532480 + SEQ_BYTES);

  // zero h-state buffers + barrier counters (ws is poisoned 0xAA each launch)
  hipMemsetAsync(ws, 0, 526336, stream);

  // raise dynamic-LDS cap to 128 KB (host-side config call, capture-safe)
  static bool lds_set = false;
  if (!lds_set) {
    hipFuncSetAttribute((const void*)lstm_fused,
                        hipFuncAttributeMaxDynamicSharedMemorySize, 131072);
    lds_set = true;
  }

  lstm_fused<<<96, 256, 131072, stream>>>(
      w_ih1, w_hh1, b_ih1, b_hh1, w_ih2, w_hh2, b_ih2, b_hh2,
      w_ih3, w_hh3, b_ih3, b_hh3, w_ih4, w_hh4, b_ih4, b_hh4,
      x, C1, Yb, h1b, h2b, grpc, rootc);
  fc_out<<<1024, 256, 0, stream>>>(Yb, fc_w, fc_b, bfc_w, bfc_b, (float*)d_out);
}